// Round 1
// baseline (500.688 us; speedup 1.0000x reference)
//
#include <hip/hip_runtime.h>
#include <hip/hip_bf16.h>

#define G_      4
#define NVP     3000
#define NCP     1000
#define DEG     8
#define NV      (G_*NVP)      // 12000
#define NC      (G_*NCP)      // 4000
#define NN      (NV+NC)       // 16000
#define NE      (NV*DEG)      // 96000
#define DF      64
#define DH      128
#define DO      64
#define KB      8
#define NB      (G_*KB)       // 32 break nodes
#define MAXR    160
#define MAXJ    640

// ---------------- setup kernels ----------------

__global__ void k_count(const int* __restrict__ conArr, int* __restrict__ condeg) {
    int e = blockIdx.x*256 + threadIdx.x;
    if (e < NE) atomicAdd(&condeg[conArr[e]], 1);
}

__global__ void k_dinv(const int* __restrict__ condeg, float* __restrict__ dinv) {
    int i = blockIdx.x*256 + threadIdx.x;
    if (i >= NN) return;
    int deg = (i < NV) ? (DEG+1) : (condeg[i-NV]+1);
    dinv[i] = 1.0f / sqrtf((float)deg);
}

__global__ void k_scan(const int* __restrict__ condeg, int* __restrict__ csr_off,
                       int* __restrict__ csr_cur) {
    __shared__ int part[256];
    __shared__ int partsum[257];
    int tid = threadIdx.x;
    const int CH = 16; // 256*16 = 4096 >= NC
    int s = 0;
    for (int k = 0; k < CH; ++k) { int idx = tid*CH + k; if (idx < NC) s += condeg[idx]; }
    part[tid] = s;
    __syncthreads();
    if (tid == 0) { int acc = 0; for (int t = 0; t < 256; ++t) { partsum[t] = acc; acc += part[t]; } partsum[256] = acc; }
    __syncthreads();
    int acc = partsum[tid];
    for (int k = 0; k < CH; ++k) {
        int idx = tid*CH + k;
        if (idx < NC) { csr_off[idx] = acc; csr_cur[idx] = acc; acc += condeg[idx]; }
    }
    if (tid == 255) csr_off[NC] = acc;
}

__global__ void k_fill(const int* __restrict__ conArr, int* __restrict__ csr_cur,
                       int* __restrict__ csr_e) {
    int e = blockIdx.x*256 + threadIdx.x;
    if (e < NE) { int p = atomicAdd(&csr_cur[conArr[e]], 1); csr_e[p] = e; }
}

// deterministic layout: sort each row's edge list ascending
__global__ void k_sort(const int* __restrict__ csr_off, int* __restrict__ csr_e) {
    int c = blockIdx.x*256 + threadIdx.x;
    if (c >= NC) return;
    int s = csr_off[c], e1 = csr_off[c+1];
    for (int a = s+1; a < e1; ++a) {
        int key = csr_e[a]; int b = a-1;
        while (b >= s && csr_e[b] > key) { csr_e[b+1] = csr_e[b]; --b; }
        csr_e[b+1] = key;
    }
}

__global__ void k_nodeval(const float* __restrict__ dinv, const int* __restrict__ conArr,
                          const int* __restrict__ varArr, const int* __restrict__ csr_off,
                          const int* __restrict__ csr_e, float* __restrict__ nodeval) {
    int i = blockIdx.x*256 + threadIdx.x;
    if (i >= NN) return;
    float di = dinv[i]; float s = 0.f;
    if (i < NV) {
        int e0 = i*DEG;
        #pragma unroll
        for (int k = 0; k < DEG; ++k) s += di * dinv[NV + conArr[e0+k]];
    } else {
        int c = i - NV;
        for (int p = csr_off[c]; p < csr_off[c+1]; ++p) s += di * dinv[varArr[csr_e[p]]];
    }
    nodeval[i] = s + di*di;
}

// top-8 per graph over [vars(3000) then cons(1000)], ties -> lower position (matches lax.top_k)
__global__ void k_topk(const float* __restrict__ nodeval, int* __restrict__ breakidx) {
    int g = blockIdx.x; int lane = threadIdx.x; // 64 threads
    __shared__ int selp[KB];
    for (int it = 0; it < KB; ++it) {
        float bv = -1e30f; int bp = 1 << 30;
        for (int p = lane; p < NVP+NCP; p += 64) {
            bool skip = false;
            for (int s = 0; s < it; ++s) if (selp[s] == p) skip = true;
            if (skip) continue;
            int node = (p < NVP) ? (g*NVP + p) : (NV + g*NCP + (p - NVP));
            float v = nodeval[node];
            if (v > bv || (v == bv && p < bp)) { bv = v; bp = p; }
        }
        for (int o = 32; o > 0; o >>= 1) {
            float ov = __shfl_xor(bv, o); int op = __shfl_xor(bp, o);
            if (ov > bv || (ov == bv && op < bp)) { bv = ov; bp = op; }
        }
        if (lane == 0) {
            selp[it] = bp;
            int node = (bp < NVP) ? (g*NVP + bp) : (NV + g*NCP + (bp - NVP));
            breakidx[g*KB + it] = node;
        }
        __syncthreads();
    }
}

// ---------------- base forward ----------------

// Z1 = X @ W1[0:64] + b1   (NN x 128)
__global__ void k_gemm1(const float* __restrict__ vf, const float* __restrict__ cf,
                        const float* __restrict__ W1, const float* __restrict__ b1,
                        float* __restrict__ Z1) {
    __shared__ float W1s[64*128];
    __shared__ float xs[2][64];
    int tid = threadIdx.x;
    for (int t = tid; t < 64*128; t += 256) W1s[t] = W1[t];
    int c = tid & 127, ry = tid >> 7;
    float bias = b1[c];
    int base = blockIdx.x * 32;
    for (int rp = 0; rp < 16; ++rp) {
        __syncthreads();
        if (tid < 128) {
            int rr = tid >> 6, k = tid & 63;
            int r2 = base + rp*2 + rr;
            const float* src = (r2 < NV) ? &vf[(size_t)r2*DF] : &cf[(size_t)(r2-NV)*DF];
            xs[rr][k] = src[k];
        }
        __syncthreads();
        float acc = bias;
        #pragma unroll
        for (int k = 0; k < 64; ++k) acc += xs[ry][k] * W1s[k*128 + c];
        Z1[(size_t)(base + rp*2 + ry)*DH + c] = acc;
    }
}

// S1 = A_hat @ Z1  (all rows, 128 ch)
__global__ void k_spmm1(const float* __restrict__ Z1, const float* __restrict__ dinv,
                        const int* __restrict__ conArr, const int* __restrict__ varArr,
                        const int* __restrict__ csr_off, const int* __restrict__ csr_e,
                        float* __restrict__ S1) {
    int i = blockIdx.x; int ch = threadIdx.x; // 128 threads
    float di = dinv[i];
    float acc = di*di * Z1[(size_t)i*DH + ch];
    if (i < NV) {
        int e0 = i*DEG;
        #pragma unroll
        for (int k = 0; k < DEG; ++k) {
            int cn = NV + conArr[e0+k];
            acc += di * dinv[cn] * Z1[(size_t)cn*DH + ch];
        }
    } else {
        int c = i - NV;
        int p0 = csr_off[c], p1 = csr_off[c+1];
        for (int p = p0; p < p1; ++p) {
            int v = varArr[csr_e[p]];
            acc += di * dinv[v] * Z1[(size_t)v*DH + ch];
        }
    }
    S1[(size_t)i*DH + ch] = acc;
}

// Z2 = relu(S1) @ W2 + b2   (NN x 64)
__global__ void k_gemm2(const float* __restrict__ S1, const float* __restrict__ W2,
                        const float* __restrict__ b2, float* __restrict__ Z2) {
    __shared__ float W2s[128*64];
    __shared__ float rs[4][128];
    int tid = threadIdx.x;
    for (int t = tid; t < 128*64; t += 256) W2s[t] = W2[t];
    int c = tid & 63, ry = tid >> 6;
    float bias = b2[c];
    int base = blockIdx.x * 32;
    for (int rp = 0; rp < 8; ++rp) {
        __syncthreads();
        {
            int rr = tid >> 7, k = tid & 127;
            float v0 = S1[(size_t)(base + rp*4 + rr)*DH + k];
            rs[rr][k] = v0 > 0.f ? v0 : 0.f;
            float v1 = S1[(size_t)(base + rp*4 + rr + 2)*DH + k];
            rs[rr+2][k] = v1 > 0.f ? v1 : 0.f;
        }
        __syncthreads();
        float acc = bias;
        #pragma unroll
        for (int k = 0; k < 128; ++k) acc += rs[ry][k] * W2s[k*64 + c];
        Z2[(size_t)(base + rp*4 + ry)*DO + c] = acc;
    }
}

// out = (A_hat @ Z2) at variable rows only, fused LayerNorm
__global__ void k_spmm2ln(const float* __restrict__ Z2, const float* __restrict__ dinv,
                          const int* __restrict__ conArr, const float* __restrict__ gamma,
                          const float* __restrict__ beta, float* __restrict__ outvar,
                          float* __restrict__ holo) {
    int v = blockIdx.x*4 + threadIdx.y;
    int ch = threadIdx.x; // 64
    float dv = dinv[v];
    float acc = dv*dv * Z2[(size_t)v*DO + ch];
    int e0 = v*DEG;
    #pragma unroll
    for (int k = 0; k < DEG; ++k) {
        int cn = NV + conArr[e0+k];
        acc += dv * dinv[cn] * Z2[(size_t)cn*DO + ch];
    }
    outvar[(size_t)v*DO + ch] = acc;
    float s = acc;
    for (int o = 32; o > 0; o >>= 1) s += __shfl_xor(s, o);
    float mu = s * (1.f/64.f);
    float d = acc - mu;
    float vs = d*d;
    for (int o = 32; o > 0; o >>= 1) vs += __shfl_xor(vs, o);
    float rstd = 1.0f / sqrtf(vs*(1.f/64.f) + 1e-5f);
    holo[(size_t)v*DO + ch] = d*rstd*gamma[ch] + beta[ch];
}

// ---------------- corrections ----------------

// per break node: build R = nbrs(i)+self with weights A[r,i], compute
// dz2[r] = (relu(S1[r]+A[r,i]*w1last) - relu(S1[r])) @ W2
__global__ void k_corr_a(const int* __restrict__ breakidx, const float* __restrict__ dinv,
                         const int* __restrict__ conArr, const int* __restrict__ varArr,
                         const int* __restrict__ csr_off, const int* __restrict__ csr_e,
                         const float* __restrict__ S1, const float* __restrict__ W1,
                         const float* __restrict__ W2,
                         int* __restrict__ RnG, float* __restrict__ RwG,
                         int* __restrict__ nRG, float* __restrict__ dz2G) {
    __shared__ float W2s[128*64];
    __shared__ int Rn[MAXR];
    __shared__ float Rw[MAXR];
    __shared__ float dh[2][128];
    __shared__ int nR_s;
    int b = blockIdx.x; int tid = threadIdx.x;
    int i = breakidx[b];
    for (int t = tid; t < 128*64; t += 256) W2s[t] = W2[t];
    if (tid == 0) {
        int n = 0; float di = dinv[i];
        if (i >= NV) {
            int c = i - NV;
            int p = csr_off[c], e1 = csr_off[c+1];
            while (p < e1 && n < MAXR-1) {
                int v = varArr[csr_e[p]]; int m = 1; ++p;
                while (p < e1 && varArr[csr_e[p]] == v) { ++m; ++p; }
                Rn[n] = v; Rw[n] = (float)m * dinv[v] * di; ++n;
            }
        } else {
            int cn[DEG];
            for (int k = 0; k < DEG; ++k) cn[k] = NV + conArr[i*DEG + k];
            for (int a = 1; a < DEG; ++a) { int key = cn[a]; int bb = a-1;
                while (bb >= 0 && cn[bb] > key) { cn[bb+1] = cn[bb]; --bb; } cn[bb+1] = key; }
            int k = 0;
            while (k < DEG) { int u = cn[k]; int m = 1; ++k;
                while (k < DEG && cn[k] == u) { ++m; ++k; }
                Rn[n] = u; Rw[n] = (float)m * dinv[u] * di; ++n; }
        }
        Rn[n] = i; Rw[n] = di*di; ++n; // self loop, last slot
        nR_s = n;
    }
    __syncthreads();
    int nR = nR_s;
    for (int t = tid; t < nR; t += 256) { RnG[b*MAXR + t] = Rn[t]; RwG[b*MAXR + t] = Rw[t]; }
    if (tid == 0) nRG[b] = nR;
    for (int r0 = 0; r0 < nR; r0 += 2) {
        __syncthreads();
        {
            int ty = tid >> 7, k = tid & 127;
            int r = r0 + ty;
            if (r < nR) {
                float s1 = S1[(size_t)Rn[r]*DH + k];
                float a = s1 + Rw[r] * W1[64*128 + k];
                dh[ty][k] = (a > 0.f ? a : 0.f) - (s1 > 0.f ? s1 : 0.f);
            }
        }
        __syncthreads();
        if (tid < 128) {
            int ty2 = tid >> 6, c = tid & 63;
            int r2 = r0 + ty2;
            if (r2 < nR) {
                float acc = 0.f;
                #pragma unroll
                for (int kk = 0; kk < 128; ++kk) acc += dh[ty2][kk] * W2s[kk*64 + c];
                dz2G[((size_t)b*MAXR + r2)*DO + c] = acc;
            }
        }
    }
}

// per graph (serial over its 8 breaks -> deterministic), accumulate LN(out+delta)-LN(out)
__global__ void k_corr_b(const int* __restrict__ RnG, const float* __restrict__ RwG,
                         const int* __restrict__ nRG, const float* __restrict__ dz2G,
                         const int* __restrict__ breakidx, const float* __restrict__ dinv,
                         const int* __restrict__ conArr, const int* __restrict__ varArr,
                         const int* __restrict__ csr_off, const int* __restrict__ csr_e,
                         const float* __restrict__ outvar, const float* __restrict__ holo,
                         const float* __restrict__ gamma, const float* __restrict__ beta,
                         float* __restrict__ accum) {
    int g = blockIdx.x;
    int lane = threadIdx.x & 63, wv = threadIdx.x >> 6;
    __shared__ int Jn[MAXJ];
    __shared__ int nJ_s;
    for (int bi = 0; bi < KB; ++bi) {
        int b = g*KB + bi;
        int i = breakidx[b];
        int nR = nRG[b];
        if (i >= NV) {
            int nJ = nR - 1;
            const float* dzi = &dz2G[((size_t)b*MAXR + (nR-1))*DO];
            for (int j0 = wv; j0 < nJ; j0 += 4) {
                int j = RnG[b*MAXR + j0];
                float aji = RwG[b*MAXR + j0];
                float dj = dinv[j];
                float x = outvar[(size_t)j*DO + lane]
                        + aji * dzi[lane]
                        + dj*dj * dz2G[((size_t)b*MAXR + j0)*DO + lane];
                float s = x; for (int o = 32; o > 0; o >>= 1) s += __shfl_xor(s, o);
                float mu = s * (1.f/64.f);
                float d = x - mu;
                float vs = d*d; for (int o = 32; o > 0; o >>= 1) vs += __shfl_xor(vs, o);
                float rstd = 1.0f / sqrtf(vs*(1.f/64.f) + 1e-5f);
                float hn = d*rstd*gamma[lane] + beta[lane];
                accum[(size_t)j*DO + lane] += hn - holo[(size_t)j*DO + lane];
            }
        } else {
            // variable break node (defensive; analytically never the top-k winner)
            if (threadIdx.x == 0) {
                int n = 0; Jn[n++] = i;
                for (int r = 0; r < nR-1; ++r) {
                    int c = RnG[b*MAXR + r] - NV;
                    for (int p = csr_off[c]; p < csr_off[c+1]; ++p) {
                        int u = varArr[csr_e[p]];
                        if (p > csr_off[c] && varArr[csr_e[p-1]] == u) continue;
                        bool found = false;
                        for (int q = 0; q < n; ++q) if (Jn[q] == u) { found = true; break; }
                        if (!found && n < MAXJ) Jn[n++] = u;
                    }
                }
                nJ_s = n;
            }
            __syncthreads();
            int nJ = nJ_s;
            for (int j0 = wv; j0 < nJ; j0 += 4) {
                int j = Jn[j0];
                float dj = dinv[j];
                float x = outvar[(size_t)j*DO + lane];
                for (int k = 0; k < DEG; ++k) {
                    int cn = NV + conArr[j*DEG + k];
                    for (int r = 0; r < nR-1; ++r)
                        if (RnG[b*MAXR + r] == cn) {
                            x += dj * dinv[cn] * dz2G[((size_t)b*MAXR + r)*DO + lane];
                            break;
                        }
                }
                if (j == i) x += dj*dj * dz2G[((size_t)b*MAXR + nR-1)*DO + lane];
                float s = x; for (int o = 32; o > 0; o >>= 1) s += __shfl_xor(s, o);
                float mu = s * (1.f/64.f);
                float d = x - mu;
                float vs = d*d; for (int o = 32; o > 0; o >>= 1) vs += __shfl_xor(vs, o);
                float rstd = 1.0f / sqrtf(vs*(1.f/64.f) + 1e-5f);
                float hn = d*rstd*gamma[lane] + beta[lane];
                accum[(size_t)j*DO + lane] += hn - holo[(size_t)j*DO + lane];
            }
        }
        __syncthreads();
    }
}

__global__ void k_final(const float* __restrict__ holo, const float* __restrict__ accum,
                        float* __restrict__ out) {
    int idx = blockIdx.x*256 + threadIdx.x;
    if (idx < NV*DO) out[idx] = holo[idx] + 0.125f * accum[idx];
}

// ---------------- launch ----------------

extern "C" void kernel_launch(void* const* d_in, const int* in_sizes, int n_in,
                              void* d_out, int out_size, void* d_ws, size_t ws_size,
                              hipStream_t stream) {
    const float* vf    = (const float*)d_in[0];
    const float* cf    = (const float*)d_in[1];
    const float* W1    = (const float*)d_in[2];
    const float* b1    = (const float*)d_in[3];
    const float* W2    = (const float*)d_in[4];
    const float* b2    = (const float*)d_in[5];
    const float* gamma = (const float*)d_in[6];
    const float* beta  = (const float*)d_in[7];
    const int*   ei    = (const int*)d_in[8];   // [0..NE) = con, [NE..2NE) = var
    const int*   conArr = ei;
    const int*   varArr = ei + NE;
    float* out = (float*)d_out;

    char* ws = (char*)d_ws;
    size_t off = 0;
    auto alloc = [&](size_t bytes) { char* p = ws + off; off = (off + bytes + 255) & ~(size_t)255; return p; };
    float* dinv    = (float*)alloc(NN*4);
    int*   condeg  = (int*)  alloc(NC*4);
    int*   csr_off = (int*)  alloc((NC+1)*4);
    int*   csr_cur = (int*)  alloc(NC*4);
    int*   csr_e   = (int*)  alloc(NE*4);
    float* nodeval = (float*)alloc(NN*4);
    int*   breakix = (int*)  alloc(NB*4);
    float* S1      = (float*)alloc((size_t)NN*DH*4);
    float* Zbuf    = (float*)alloc((size_t)NN*DH*4);   // Z1, later Z2 + outvar
    float* holo    = (float*)alloc((size_t)NV*DO*4);
    float* accum   = (float*)alloc((size_t)NV*DO*4);
    int*   RnG     = (int*)  alloc(NB*MAXR*4);
    float* RwG     = (float*)alloc(NB*MAXR*4);
    int*   nRG     = (int*)  alloc(NB*4);
    float* dz2G    = (float*)alloc((size_t)NB*MAXR*DO*4);
    float* Z1 = Zbuf;
    float* Z2 = Zbuf;                       // Z1 dead by then
    float* outvar = Zbuf + (size_t)NN*DO;   // upper part of Zbuf

    hipMemsetAsync(condeg, 0, NC*4, stream);
    hipMemsetAsync(accum, 0, (size_t)NV*DO*4, stream);

    k_count  <<<(NE+255)/256, 256, 0, stream>>>(conArr, condeg);
    k_dinv   <<<(NN+255)/256, 256, 0, stream>>>(condeg, dinv);
    k_scan   <<<1, 256, 0, stream>>>(condeg, csr_off, csr_cur);
    k_fill   <<<(NE+255)/256, 256, 0, stream>>>(conArr, csr_cur, csr_e);
    k_sort   <<<(NC+255)/256, 256, 0, stream>>>(csr_off, csr_e);
    k_nodeval<<<(NN+255)/256, 256, 0, stream>>>(dinv, conArr, varArr, csr_off, csr_e, nodeval);
    k_topk   <<<G_, 64, 0, stream>>>(nodeval, breakix);

    k_gemm1  <<<NN/32, 256, 0, stream>>>(vf, cf, W1, b1, Z1);
    k_spmm1  <<<NN, 128, 0, stream>>>(Z1, dinv, conArr, varArr, csr_off, csr_e, S1);
    k_gemm2  <<<NN/32, 256, 0, stream>>>(S1, W2, b2, Z2);
    k_spmm2ln<<<NV/4, dim3(64,4), 0, stream>>>(Z2, dinv, conArr, gamma, beta, outvar, holo);

    k_corr_a <<<NB, 256, 0, stream>>>(breakix, dinv, conArr, varArr, csr_off, csr_e,
                                      S1, W1, W2, RnG, RwG, nRG, dz2G);
    k_corr_b <<<G_, 256, 0, stream>>>(RnG, RwG, nRG, dz2G, breakix, dinv, conArr, varArr,
                                      csr_off, csr_e, outvar, holo, gamma, beta, accum);
    k_final  <<<(NV*DO+255)/256, 256, 0, stream>>>(holo, accum, out);
}

// Round 2
// 220.972 us; speedup vs baseline: 2.2658x; 2.2658x over previous
//
#include <hip/hip_runtime.h>
#include <hip/hip_bf16.h>

#define G_      4
#define NVP     3000
#define NCP     1000
#define DEG     8
#define NV      (G_*NVP)      // 12000
#define NC      (G_*NCP)      // 4000
#define NN      (NV+NC)       // 16000
#define NE      (NV*DEG)      // 96000
#define DF      64
#define DH      128
#define DO      64
#define KB      8
#define NB      (G_*KB)       // 32 break nodes
#define MAXR    160
#define MAXJ    640

// ---------------- setup kernels ----------------

__global__ void k_count(const int* __restrict__ conArr, int* __restrict__ condeg) {
    int e = blockIdx.x*256 + threadIdx.x;
    if (e < NE) atomicAdd(&condeg[conArr[e]], 1);
}

__global__ void k_dinv(const int* __restrict__ condeg, float* __restrict__ dinv) {
    int i = blockIdx.x*256 + threadIdx.x;
    if (i >= NN) return;
    int deg = (i < NV) ? (DEG+1) : (condeg[i-NV]+1);
    dinv[i] = 1.0f / sqrtf((float)deg);
}

__global__ void k_scan(const int* __restrict__ condeg, int* __restrict__ csr_off,
                       int* __restrict__ csr_cur) {
    __shared__ int part[256];
    __shared__ int partsum[257];
    int tid = threadIdx.x;
    const int CH = 16; // 256*16 = 4096 >= NC
    int s = 0;
    for (int k = 0; k < CH; ++k) { int idx = tid*CH + k; if (idx < NC) s += condeg[idx]; }
    part[tid] = s;
    __syncthreads();
    if (tid == 0) { int acc = 0; for (int t = 0; t < 256; ++t) { partsum[t] = acc; acc += part[t]; } partsum[256] = acc; }
    __syncthreads();
    int acc = partsum[tid];
    for (int k = 0; k < CH; ++k) {
        int idx = tid*CH + k;
        if (idx < NC) { csr_off[idx] = acc; csr_cur[idx] = acc; acc += condeg[idx]; }
    }
    if (tid == 255) csr_off[NC] = acc;
}

__global__ void k_fill(const int* __restrict__ conArr, int* __restrict__ csr_cur,
                       int* __restrict__ csr_e) {
    int e = blockIdx.x*256 + threadIdx.x;
    if (e < NE) { int p = atomicAdd(&csr_cur[conArr[e]], 1); csr_e[p] = e; }
}

// deterministic order: wave-parallel rank sort of each row's edge ids (unique keys).
// edge id = var*8+k, so equal-var edges end up adjacent after sorting.
__global__ void k_sortrank(const int* __restrict__ csr_off, int* __restrict__ csr_e,
                           const int* __restrict__ varArr, int* __restrict__ csr_v) {
    int row = blockIdx.x*4 + (threadIdx.x >> 6);
    int l = threadIdx.x & 63;
    if (row >= NC) return;
    int s = csr_off[row], e1 = csr_off[row+1];
    int len = e1 - s;
    if (len > 64) {            // slow path, statistically unreachable (mean 24)
        if (l == 0) {
            for (int a = s+1; a < e1; ++a) {
                int key = csr_e[a]; int b = a-1;
                while (b >= s && csr_e[b] > key) { csr_e[b+1] = csr_e[b]; --b; }
                csr_e[b+1] = key;
            }
            for (int p = s; p < e1; ++p) csr_v[p] = varArr[csr_e[p]];
        }
        return;
    }
    int key = (l < len) ? csr_e[s + l] : 0x7fffffff;
    int rank = 0;
    for (int m = 0; m < len; ++m) {
        int km = __shfl(key, m);
        if (l < len && km < key) rank++;
    }
    if (l < len) {
        csr_e[s + rank] = key;
        csr_v[s + rank] = varArr[key];
    }
}

__global__ void k_nodeval(const float* __restrict__ dinv, const int* __restrict__ conArr,
                          const int* __restrict__ csr_off, const int* __restrict__ csr_v,
                          float* __restrict__ nodeval) {
    int i = blockIdx.x*256 + threadIdx.x;
    if (i >= NN) return;
    float di = dinv[i]; float s = 0.f;
    if (i < NV) {
        int e0 = i*DEG;
        #pragma unroll
        for (int k = 0; k < DEG; ++k) s += di * dinv[NV + conArr[e0+k]];
    } else {
        int c = i - NV;
        for (int p = csr_off[c]; p < csr_off[c+1]; ++p) s += di * dinv[csr_v[p]];
    }
    nodeval[i] = s + di*di;
}

// top-8 per graph, ties -> lower position (matches lax.top_k)
__global__ void k_topk(const float* __restrict__ nodeval, int* __restrict__ breakidx) {
    int g = blockIdx.x; int tid = threadIdx.x; // 256
    int lane = tid & 63, w = tid >> 6;
    __shared__ int selp[KB];
    __shared__ float swv[4]; __shared__ int swp[4];
    for (int it = 0; it < KB; ++it) {
        float bv = -1e30f; int bp = 1 << 30;
        for (int p = tid; p < NVP+NCP; p += 256) {
            bool skip = false;
            for (int s = 0; s < it; ++s) if (selp[s] == p) skip = true;
            if (skip) continue;
            int node = (p < NVP) ? (g*NVP + p) : (NV + g*NCP + (p - NVP));
            float v = nodeval[node];
            if (v > bv || (v == bv && p < bp)) { bv = v; bp = p; }
        }
        for (int o = 32; o > 0; o >>= 1) {
            float ov = __shfl_xor(bv, o); int op = __shfl_xor(bp, o);
            if (ov > bv || (ov == bv && op < bp)) { bv = ov; bp = op; }
        }
        if (lane == 0) { swv[w] = bv; swp[w] = bp; }
        __syncthreads();
        if (tid == 0) {
            float fv = swv[0]; int fp = swp[0];
            for (int t = 1; t < 4; ++t)
                if (swv[t] > fv || (swv[t] == fv && swp[t] < fp)) { fv = swv[t]; fp = swp[t]; }
            selp[it] = fp;
            int node = (fp < NVP) ? (g*NVP + fp) : (NV + g*NCP + (fp - NVP));
            breakidx[g*KB + it] = node;
        }
        __syncthreads();
    }
}

// ---------------- base forward ----------------

// Z1y = dinv * (X @ W1[0:64] + b1)   (NN x 128)
__global__ void k_gemm1(const float* __restrict__ vf, const float* __restrict__ cf,
                        const float* __restrict__ W1, const float* __restrict__ b1,
                        const float* __restrict__ dinv, float* __restrict__ Z1y) {
    __shared__ float W1s[64*128];   // 32 KB
    __shared__ float xs[8][64];
    int tid = threadIdx.x;
    for (int t = tid; t < 64*128; t += 256) W1s[t] = W1[t];
    int c = tid & 127, half = tid >> 7;
    float bias = b1[c];
    int base = blockIdx.x * 32;
    for (int t8 = 0; t8 < 4; ++t8) {
        int r0 = base + t8*8;
        __syncthreads();
        for (int t = tid; t < 512; t += 256) {
            int rr = t >> 6, k = t & 63;
            int r = r0 + rr;
            const float* src = (r < NV) ? &vf[(size_t)r*DF] : &cf[(size_t)(r-NV)*DF];
            xs[rr][k] = src[k];
        }
        __syncthreads();
        float acc0 = bias, acc1 = bias, acc2 = bias, acc3 = bias;
        int rb = half*4;
        #pragma unroll
        for (int k = 0; k < 64; ++k) {
            float wv = W1s[k*128 + c];
            acc0 += xs[rb+0][k] * wv;
            acc1 += xs[rb+1][k] * wv;
            acc2 += xs[rb+2][k] * wv;
            acc3 += xs[rb+3][k] * wv;
        }
        int r = r0 + rb;
        Z1y[(size_t)(r+0)*DH + c] = acc0 * dinv[r+0];
        Z1y[(size_t)(r+1)*DH + c] = acc1 * dinv[r+1];
        Z1y[(size_t)(r+2)*DH + c] = acc2 * dinv[r+2];
        Z1y[(size_t)(r+3)*DH + c] = acc3 * dinv[r+3];
    }
}

// S1 = dinv_i * (Z1y[i] + sum_nbr Z1y[j])
__global__ void k_spmm1(const float* __restrict__ Z1y, const float* __restrict__ dinv,
                        const int* __restrict__ conArr, const int* __restrict__ csr_off,
                        const int* __restrict__ csr_v, float* __restrict__ S1) {
    int i = blockIdx.x*2 + (threadIdx.x >> 7);
    int ch = threadIdx.x & 127;
    float acc = Z1y[(size_t)i*DH + ch];
    if (i < NV) {
        int e0 = i*DEG;
        #pragma unroll
        for (int k = 0; k < DEG; ++k)
            acc += Z1y[(size_t)(NV + conArr[e0+k])*DH + ch];
    } else {
        int c = i - NV;
        int p0 = csr_off[c], p1 = csr_off[c+1];
        for (int p = p0; p < p1; ++p)
            acc += Z1y[(size_t)csr_v[p]*DH + ch];
    }
    S1[(size_t)i*DH + ch] = acc * dinv[i];
}

// Z2y = dinv * (relu(S1) @ W2 + b2)   (NN x 64)
__global__ void k_gemm2(const float* __restrict__ S1, const float* __restrict__ W2,
                        const float* __restrict__ b2, const float* __restrict__ dinv,
                        float* __restrict__ Z2y) {
    __shared__ float W2s[128*64];  // 32 KB
    __shared__ float rs[8][128];
    int tid = threadIdx.x;
    for (int t = tid; t < 128*64; t += 256) W2s[t] = W2[t];
    int c = tid & 63, q = tid >> 6;
    float bias = b2[c];
    int base = blockIdx.x * 32;
    for (int t8 = 0; t8 < 4; ++t8) {
        int r0 = base + t8*8;
        __syncthreads();
        for (int t = tid; t < 1024; t += 256) {
            int rr = t >> 7, k = t & 127;
            float v = S1[(size_t)(r0+rr)*DH + k];
            rs[rr][k] = v > 0.f ? v : 0.f;
        }
        __syncthreads();
        float acc0 = bias, acc1 = bias;
        int rb = q*2;
        #pragma unroll
        for (int k = 0; k < 128; ++k) {
            float wv = W2s[k*64 + c];
            acc0 += rs[rb+0][k] * wv;
            acc1 += rs[rb+1][k] * wv;
        }
        int r = r0 + rb;
        Z2y[(size_t)(r+0)*DO + c] = acc0 * dinv[r+0];
        Z2y[(size_t)(r+1)*DO + c] = acc1 * dinv[r+1];
    }
}

// out = (A_hat @ Z2) at variable rows only, fused LayerNorm
__global__ void k_spmm2ln(const float* __restrict__ Z2y, const float* __restrict__ dinv,
                          const int* __restrict__ conArr, const float* __restrict__ gamma,
                          const float* __restrict__ beta, float* __restrict__ outvar,
                          float* __restrict__ holo) {
    int v = blockIdx.x*4 + threadIdx.y;
    int ch = threadIdx.x; // 64
    float dv = dinv[v];
    float acc = Z2y[(size_t)v*DO + ch];
    int e0 = v*DEG;
    #pragma unroll
    for (int k = 0; k < DEG; ++k)
        acc += Z2y[(size_t)(NV + conArr[e0+k])*DO + ch];
    acc *= dv;
    outvar[(size_t)v*DO + ch] = acc;
    float s = acc;
    for (int o = 32; o > 0; o >>= 1) s += __shfl_xor(s, o);
    float mu = s * (1.f/64.f);
    float d = acc - mu;
    float vs = d*d;
    for (int o = 32; o > 0; o >>= 1) vs += __shfl_xor(vs, o);
    float rstd = 1.0f / sqrtf(vs*(1.f/64.f) + 1e-5f);
    holo[(size_t)v*DO + ch] = d*rstd*gamma[ch] + beta[ch];
}

// ---------------- corrections ----------------

__global__ void k_corr_a(const int* __restrict__ breakidx, const float* __restrict__ dinv,
                         const int* __restrict__ conArr, const int* __restrict__ csr_off,
                         const int* __restrict__ csr_v,
                         const float* __restrict__ S1, const float* __restrict__ W1,
                         const float* __restrict__ W2,
                         int* __restrict__ RnG, float* __restrict__ RwG,
                         int* __restrict__ nRG, float* __restrict__ dz2G) {
    __shared__ float W2s[128*64];
    __shared__ int Rn[MAXR];
    __shared__ float Rw[MAXR];
    __shared__ float dh[4][128];
    __shared__ int nR_s;
    int b = blockIdx.x; int tid = threadIdx.x;
    int i = breakidx[b];
    for (int t = tid; t < 128*64; t += 256) W2s[t] = W2[t];
    if (tid == 0) {
        int n = 0; float di = dinv[i];
        if (i >= NV) {
            int c = i - NV;
            int p = csr_off[c], e1 = csr_off[c+1];
            while (p < e1 && n < MAXR-1) {
                int v = csr_v[p]; int m = 1; ++p;
                while (p < e1 && csr_v[p] == v) { ++m; ++p; }
                Rn[n] = v; Rw[n] = (float)m * dinv[v] * di; ++n;
            }
        } else {
            int cn[DEG];
            for (int k = 0; k < DEG; ++k) cn[k] = NV + conArr[i*DEG + k];
            for (int a = 1; a < DEG; ++a) { int key = cn[a]; int bb = a-1;
                while (bb >= 0 && cn[bb] > key) { cn[bb+1] = cn[bb]; --bb; } cn[bb+1] = key; }
            int k = 0;
            while (k < DEG) { int u = cn[k]; int m = 1; ++k;
                while (k < DEG && cn[k] == u) { ++m; ++k; }
                Rn[n] = u; Rw[n] = (float)m * dinv[u] * di; ++n; }
        }
        Rn[n] = i; Rw[n] = di*di; ++n; // self loop, last slot
        nR_s = n;
    }
    __syncthreads();
    int nR = nR_s;
    for (int t = tid; t < nR; t += 256) { RnG[b*MAXR + t] = Rn[t]; RwG[b*MAXR + t] = Rw[t]; }
    if (tid == 0) nRG[b] = nR;
    for (int r0 = 0; r0 < nR; r0 += 4) {
        __syncthreads();
        for (int t = tid; t < 512; t += 256) {
            int ty = t >> 7, k = t & 127;
            int r = r0 + ty;
            if (r < nR) {
                float s1 = S1[(size_t)Rn[r]*DH + k];
                float a = s1 + Rw[r] * W1[64*128 + k];
                dh[ty][k] = fmaxf(a, 0.f) - fmaxf(s1, 0.f);
            }
        }
        __syncthreads();
        int ty2 = tid >> 6, c = tid & 63;
        int r2 = r0 + ty2;
        if (r2 < nR) {
            float acc = 0.f;
            #pragma unroll
            for (int kk = 0; kk < 128; ++kk) acc += dh[ty2][kk] * W2s[kk*64 + c];
            dz2G[((size_t)b*MAXR + r2)*DO + c] = acc;
        }
    }
}

// per graph (serial over its 8 breaks -> deterministic), accumulate LN(out+delta)-LN(out)
__global__ void k_corr_b(const int* __restrict__ RnG, const float* __restrict__ RwG,
                         const int* __restrict__ nRG, const float* __restrict__ dz2G,
                         const int* __restrict__ breakidx, const float* __restrict__ dinv,
                         const int* __restrict__ conArr, const int* __restrict__ csr_off,
                         const int* __restrict__ csr_v,
                         const float* __restrict__ outvar, const float* __restrict__ holo,
                         const float* __restrict__ gamma, const float* __restrict__ beta,
                         float* __restrict__ accum) {
    int g = blockIdx.x;
    int lane = threadIdx.x & 63, wv = threadIdx.x >> 6; // 16 waves
    __shared__ int Jn[MAXJ];
    __shared__ int nJ_s;
    for (int bi = 0; bi < KB; ++bi) {
        int b = g*KB + bi;
        int i = breakidx[b];
        int nR = nRG[b];
        if (i >= NV) {
            int nJ = nR - 1;
            const float* dzi = &dz2G[((size_t)b*MAXR + (nR-1))*DO];
            for (int j0 = wv; j0 < nJ; j0 += 16) {
                int j = RnG[b*MAXR + j0];
                float aji = RwG[b*MAXR + j0];
                float dj = dinv[j];
                float x = outvar[(size_t)j*DO + lane]
                        + aji * dzi[lane]
                        + dj*dj * dz2G[((size_t)b*MAXR + j0)*DO + lane];
                float s = x; for (int o = 32; o > 0; o >>= 1) s += __shfl_xor(s, o);
                float mu = s * (1.f/64.f);
                float d = x - mu;
                float vs = d*d; for (int o = 32; o > 0; o >>= 1) vs += __shfl_xor(vs, o);
                float rstd = 1.0f / sqrtf(vs*(1.f/64.f) + 1e-5f);
                float hn = d*rstd*gamma[lane] + beta[lane];
                accum[(size_t)j*DO + lane] += hn - holo[(size_t)j*DO + lane];
            }
        } else {
            // variable break node (defensive; analytically never the top-k winner)
            if (threadIdx.x == 0) {
                int n = 0; Jn[n++] = i;
                for (int r = 0; r < nR-1; ++r) {
                    int c = RnG[b*MAXR + r] - NV;
                    for (int p = csr_off[c]; p < csr_off[c+1]; ++p) {
                        int u = csr_v[p];
                        if (p > csr_off[c] && csr_v[p-1] == u) continue;
                        bool found = false;
                        for (int q = 0; q < n; ++q) if (Jn[q] == u) { found = true; break; }
                        if (!found && n < MAXJ) Jn[n++] = u;
                    }
                }
                nJ_s = n;
            }
            __syncthreads();
            int nJ = nJ_s;
            for (int j0 = wv; j0 < nJ; j0 += 16) {
                int j = Jn[j0];
                float dj = dinv[j];
                float x = outvar[(size_t)j*DO + lane];
                for (int k = 0; k < DEG; ++k) {
                    int cn = NV + conArr[j*DEG + k];
                    for (int r = 0; r < nR-1; ++r)
                        if (RnG[b*MAXR + r] == cn) {
                            x += dj * dinv[cn] * dz2G[((size_t)b*MAXR + r)*DO + lane];
                            break;
                        }
                }
                if (j == i) x += dj*dj * dz2G[((size_t)b*MAXR + nR-1)*DO + lane];
                float s = x; for (int o = 32; o > 0; o >>= 1) s += __shfl_xor(s, o);
                float mu = s * (1.f/64.f);
                float d = x - mu;
                float vs = d*d; for (int o = 32; o > 0; o >>= 1) vs += __shfl_xor(vs, o);
                float rstd = 1.0f / sqrtf(vs*(1.f/64.f) + 1e-5f);
                float hn = d*rstd*gamma[lane] + beta[lane];
                accum[(size_t)j*DO + lane] += hn - holo[(size_t)j*DO + lane];
            }
        }
        __syncthreads();
    }
}

__global__ void k_final(const float* __restrict__ holo, const float* __restrict__ accum,
                        float* __restrict__ out) {
    int idx = blockIdx.x*256 + threadIdx.x;
    if (idx < NV*DO) out[idx] = holo[idx] + 0.125f * accum[idx];
}

// ---------------- launch ----------------

extern "C" void kernel_launch(void* const* d_in, const int* in_sizes, int n_in,
                              void* d_out, int out_size, void* d_ws, size_t ws_size,
                              hipStream_t stream) {
    const float* vf    = (const float*)d_in[0];
    const float* cf    = (const float*)d_in[1];
    const float* W1    = (const float*)d_in[2];
    const float* b1    = (const float*)d_in[3];
    const float* W2    = (const float*)d_in[4];
    const float* b2    = (const float*)d_in[5];
    const float* gamma = (const float*)d_in[6];
    const float* beta  = (const float*)d_in[7];
    const int*   ei    = (const int*)d_in[8];   // [0..NE) = con, [NE..2NE) = var
    const int*   conArr = ei;
    const int*   varArr = ei + NE;
    float* out = (float*)d_out;

    char* ws = (char*)d_ws;
    size_t off = 0;
    auto alloc = [&](size_t bytes) { char* p = ws + off; off = (off + bytes + 255) & ~(size_t)255; return p; };
    float* dinv    = (float*)alloc(NN*4);
    int*   condeg  = (int*)  alloc(NC*4);
    int*   csr_off = (int*)  alloc((NC+1)*4);
    int*   csr_cur = (int*)  alloc(NC*4);
    int*   csr_e   = (int*)  alloc(NE*4);
    int*   csr_v   = (int*)  alloc(NE*4);
    float* nodeval = (float*)alloc(NN*4);
    int*   breakix = (int*)  alloc(NB*4);
    float* S1      = (float*)alloc((size_t)NN*DH*4);
    float* Zbuf    = (float*)alloc((size_t)NN*DH*4);   // Z1y, later Z2y + outvar
    float* holo    = (float*)alloc((size_t)NV*DO*4);
    float* accum   = (float*)alloc((size_t)NV*DO*4);
    int*   RnG     = (int*)  alloc(NB*MAXR*4);
    float* RwG     = (float*)alloc(NB*MAXR*4);
    int*   nRG     = (int*)  alloc(NB*4);
    float* dz2G    = (float*)alloc((size_t)NB*MAXR*DO*4);
    float* Z1y = Zbuf;
    float* Z2y = Zbuf;                      // Z1y dead by then
    float* outvar = Zbuf + (size_t)NN*DO;   // upper part of Zbuf

    hipMemsetAsync(condeg, 0, NC*4, stream);
    hipMemsetAsync(accum, 0, (size_t)NV*DO*4, stream);

    k_count   <<<(NE+255)/256, 256, 0, stream>>>(conArr, condeg);
    k_dinv    <<<(NN+255)/256, 256, 0, stream>>>(condeg, dinv);
    k_scan    <<<1, 256, 0, stream>>>(condeg, csr_off, csr_cur);
    k_fill    <<<(NE+255)/256, 256, 0, stream>>>(conArr, csr_cur, csr_e);
    k_sortrank<<<(NC+3)/4, 256, 0, stream>>>(csr_off, csr_e, varArr, csr_v);
    k_nodeval <<<(NN+255)/256, 256, 0, stream>>>(dinv, conArr, csr_off, csr_v, nodeval);
    k_topk    <<<G_, 256, 0, stream>>>(nodeval, breakix);

    k_gemm1   <<<NN/32, 256, 0, stream>>>(vf, cf, W1, b1, dinv, Z1y);
    k_spmm1   <<<NN/2, 256, 0, stream>>>(Z1y, dinv, conArr, csr_off, csr_v, S1);
    k_gemm2   <<<NN/32, 256, 0, stream>>>(S1, W2, b2, dinv, Z2y);
    k_spmm2ln <<<NV/4, dim3(64,4), 0, stream>>>(Z2y, dinv, conArr, gamma, beta, outvar, holo);

    k_corr_a  <<<NB, 256, 0, stream>>>(breakix, dinv, conArr, csr_off, csr_v,
                                       S1, W1, W2, RnG, RwG, nRG, dz2G);
    k_corr_b  <<<G_, 1024, 0, stream>>>(RnG, RwG, nRG, dz2G, breakix, dinv, conArr,
                                        csr_off, csr_v, outvar, holo, gamma, beta, accum);
    k_final   <<<(NV*DO+255)/256, 256, 0, stream>>>(holo, accum, out);
}

// Round 3
// 215.223 us; speedup vs baseline: 2.3264x; 1.0267x over previous
//
#include <hip/hip_runtime.h>
#include <hip/hip_bf16.h>

#define G_      4
#define NVP     3000
#define NCP     1000
#define DEG     8
#define NV      (G_*NVP)      // 12000
#define NC      (G_*NCP)      // 4000
#define NN      (NV+NC)       // 16000
#define NE      (NV*DEG)      // 96000
#define DF      64
#define DH      128
#define DO      64
#define KB      8
#define NB      (G_*KB)       // 32 break nodes
#define MAXR    160
#define MAXJ    640

// ---------------- setup kernels ----------------

__global__ void k_zero(int* __restrict__ condeg) {
    int i = blockIdx.x*256 + threadIdx.x;
    if (i < NC) condeg[i] = 0;
}

__global__ void k_count(const int* __restrict__ conArr, int* __restrict__ condeg) {
    int e = blockIdx.x*256 + threadIdx.x;
    if (e < NE) atomicAdd(&condeg[conArr[e]], 1);
}

// exclusive scan of condeg + dinv for all nodes (single block)
__global__ void k_scan(const int* __restrict__ condeg, int* __restrict__ csr_off,
                       int* __restrict__ csr_cur, float* __restrict__ dinv) {
    __shared__ int part[256];
    __shared__ int partsum[257];
    int tid = threadIdx.x;
    const int CH = 16; // 256*16 = 4096 >= NC
    int s = 0;
    for (int k = 0; k < CH; ++k) { int idx = tid*CH + k; if (idx < NC) s += condeg[idx]; }
    part[tid] = s;
    __syncthreads();
    if (tid == 0) { int acc = 0; for (int t = 0; t < 256; ++t) { partsum[t] = acc; acc += part[t]; } partsum[256] = acc; }
    __syncthreads();
    int acc = partsum[tid];
    for (int k = 0; k < CH; ++k) {
        int idx = tid*CH + k;
        if (idx < NC) { csr_off[idx] = acc; csr_cur[idx] = acc; acc += condeg[idx]; }
    }
    if (tid == 255) csr_off[NC] = acc;
    // dinv: vars all have deg 9
    const float dv = 0.333333333333333f; // rsqrt(9)
    for (int i = tid; i < NV; i += 256) dinv[i] = dv;
    for (int i = tid; i < NC; i += 256) dinv[NV + i] = 1.0f / sqrtf((float)(condeg[i] + 1));
}

__global__ void k_fill(const int* __restrict__ conArr, int* __restrict__ csr_cur,
                       int* __restrict__ csr_e) {
    int e = blockIdx.x*256 + threadIdx.x;
    if (e < NE) { int p = atomicAdd(&csr_cur[conArr[e]], 1); csr_e[p] = e; }
}

// deterministic order: wave-parallel rank sort of each row's edge ids (unique keys).
// edge id = var*8+k, so equal-var edges end up adjacent after sorting.
__global__ void k_sortrank(const int* __restrict__ csr_off, int* __restrict__ csr_e,
                           const int* __restrict__ varArr, int* __restrict__ csr_v) {
    int row = blockIdx.x*4 + (threadIdx.x >> 6);
    int l = threadIdx.x & 63;
    if (row >= NC) return;
    int s = csr_off[row], e1 = csr_off[row+1];
    int len = e1 - s;
    if (len > 64) {            // slow path, statistically unreachable (mean 24)
        if (l == 0) {
            for (int a = s+1; a < e1; ++a) {
                int key = csr_e[a]; int b = a-1;
                while (b >= s && csr_e[b] > key) { csr_e[b+1] = csr_e[b]; --b; }
                csr_e[b+1] = key;
            }
            for (int p = s; p < e1; ++p) csr_v[p] = varArr[csr_e[p]];
        }
        return;
    }
    int key = (l < len) ? csr_e[s + l] : 0x7fffffff;
    int rank = 0;
    for (int m = 0; m < len; ++m) {
        int km = __shfl(key, m);
        if (l < len && km < key) rank++;
    }
    if (l < len) {
        csr_e[s + rank] = key;
        csr_v[s + rank] = varArr[key];
    }
}

__global__ void k_nodeval(const float* __restrict__ dinv, const int* __restrict__ conArr,
                          const int* __restrict__ csr_off, const int* __restrict__ csr_v,
                          float* __restrict__ nodeval) {
    int i = blockIdx.x*256 + threadIdx.x;
    if (i >= NN) return;
    float di = dinv[i]; float s = 0.f;
    if (i < NV) {
        int e0 = i*DEG;
        #pragma unroll
        for (int k = 0; k < DEG; ++k) s += di * dinv[NV + conArr[e0+k]];
    } else {
        int c = i - NV;
        for (int p = csr_off[c]; p < csr_off[c+1]; ++p) s += di * dinv[csr_v[p]];
    }
    nodeval[i] = s + di*di;
}

// top-8 per graph, ties -> lower position (matches lax.top_k)
__global__ void k_topk(const float* __restrict__ nodeval, int* __restrict__ breakidx) {
    int g = blockIdx.x; int tid = threadIdx.x; // 256
    int lane = tid & 63, w = tid >> 6;
    __shared__ int selp[KB];
    __shared__ float swv[4]; __shared__ int swp[4];
    for (int it = 0; it < KB; ++it) {
        float bv = -1e30f; int bp = 1 << 30;
        for (int p = tid; p < NVP+NCP; p += 256) {
            bool skip = false;
            for (int s = 0; s < it; ++s) if (selp[s] == p) skip = true;
            if (skip) continue;
            int node = (p < NVP) ? (g*NVP + p) : (NV + g*NCP + (p - NVP));
            float v = nodeval[node];
            if (v > bv || (v == bv && p < bp)) { bv = v; bp = p; }
        }
        for (int o = 32; o > 0; o >>= 1) {
            float ov = __shfl_xor(bv, o); int op = __shfl_xor(bp, o);
            if (ov > bv || (ov == bv && op < bp)) { bv = ov; bp = op; }
        }
        if (lane == 0) { swv[w] = bv; swp[w] = bp; }
        __syncthreads();
        if (tid == 0) {
            float fv = swv[0]; int fp = swp[0];
            for (int t = 1; t < 4; ++t)
                if (swv[t] > fv || (swv[t] == fv && swp[t] < fp)) { fv = swv[t]; fp = swp[t]; }
            selp[it] = fp;
            int node = (fp < NVP) ? (g*NVP + fp) : (NV + g*NCP + (fp - NVP));
            breakidx[g*KB + it] = node;
        }
        __syncthreads();
    }
}

// ---------------- base forward ----------------

// Z1y = dinv * (X @ W1[0:64] + b1)   (NN x 128)
__global__ void k_gemm1(const float* __restrict__ vf, const float* __restrict__ cf,
                        const float* __restrict__ W1, const float* __restrict__ b1,
                        const float* __restrict__ dinv, float* __restrict__ Z1y) {
    __shared__ float W1s[64*128];   // 32 KB
    __shared__ float xs[8][64];
    int tid = threadIdx.x;
    for (int t = tid; t < 64*128; t += 256) W1s[t] = W1[t];
    int c = tid & 127, half = tid >> 7;
    float bias = b1[c];
    int base = blockIdx.x * 32;
    for (int t8 = 0; t8 < 4; ++t8) {
        int r0 = base + t8*8;
        __syncthreads();
        for (int t = tid; t < 512; t += 256) {
            int rr = t >> 6, k = t & 63;
            int r = r0 + rr;
            const float* src = (r < NV) ? &vf[(size_t)r*DF] : &cf[(size_t)(r-NV)*DF];
            xs[rr][k] = src[k];
        }
        __syncthreads();
        float acc0 = bias, acc1 = bias, acc2 = bias, acc3 = bias;
        int rb = half*4;
        #pragma unroll
        for (int k = 0; k < 64; ++k) {
            float wv = W1s[k*128 + c];
            acc0 += xs[rb+0][k] * wv;
            acc1 += xs[rb+1][k] * wv;
            acc2 += xs[rb+2][k] * wv;
            acc3 += xs[rb+3][k] * wv;
        }
        int r = r0 + rb;
        Z1y[(size_t)(r+0)*DH + c] = acc0 * dinv[r+0];
        Z1y[(size_t)(r+1)*DH + c] = acc1 * dinv[r+1];
        Z1y[(size_t)(r+2)*DH + c] = acc2 * dinv[r+2];
        Z1y[(size_t)(r+3)*DH + c] = acc3 * dinv[r+3];
    }
}

// S1 = dinv_i * (Z1y[i] + sum_nbr Z1y[j])
__global__ void k_spmm1(const float* __restrict__ Z1y, const float* __restrict__ dinv,
                        const int* __restrict__ conArr, const int* __restrict__ csr_off,
                        const int* __restrict__ csr_v, float* __restrict__ S1) {
    int i = blockIdx.x*2 + (threadIdx.x >> 7);
    int ch = threadIdx.x & 127;
    float acc = Z1y[(size_t)i*DH + ch];
    if (i < NV) {
        int e0 = i*DEG;
        #pragma unroll
        for (int k = 0; k < DEG; ++k)
            acc += Z1y[(size_t)(NV + conArr[e0+k])*DH + ch];
    } else {
        int c = i - NV;
        int p0 = csr_off[c], p1 = csr_off[c+1];
        for (int p = p0; p < p1; ++p)
            acc += Z1y[(size_t)csr_v[p]*DH + ch];
    }
    S1[(size_t)i*DH + ch] = acc * dinv[i];
}

// Z2y = dinv * (relu(S1) @ W2 + b2)   (NN x 64)
__global__ void k_gemm2(const float* __restrict__ S1, const float* __restrict__ W2,
                        const float* __restrict__ b2, const float* __restrict__ dinv,
                        float* __restrict__ Z2y) {
    __shared__ float W2s[128*64];  // 32 KB
    __shared__ float rs[8][128];
    int tid = threadIdx.x;
    for (int t = tid; t < 128*64; t += 256) W2s[t] = W2[t];
    int c = tid & 63, q = tid >> 6;
    float bias = b2[c];
    int base = blockIdx.x * 32;
    for (int t8 = 0; t8 < 4; ++t8) {
        int r0 = base + t8*8;
        __syncthreads();
        for (int t = tid; t < 1024; t += 256) {
            int rr = t >> 7, k = t & 127;
            float v = S1[(size_t)(r0+rr)*DH + k];
            rs[rr][k] = v > 0.f ? v : 0.f;
        }
        __syncthreads();
        float acc0 = bias, acc1 = bias;
        int rb = q*2;
        #pragma unroll
        for (int k = 0; k < 128; ++k) {
            float wv = W2s[k*64 + c];
            acc0 += rs[rb+0][k] * wv;
            acc1 += rs[rb+1][k] * wv;
        }
        int r = r0 + rb;
        Z2y[(size_t)(r+0)*DO + c] = acc0 * dinv[r+0];
        Z2y[(size_t)(r+1)*DO + c] = acc1 * dinv[r+1];
    }
}

// out = (A_hat @ Z2) at variable rows only, fused LayerNorm; writes holo scratch AND d_out
__global__ void k_spmm2ln(const float* __restrict__ Z2y, const float* __restrict__ dinv,
                          const int* __restrict__ conArr, const float* __restrict__ gamma,
                          const float* __restrict__ beta, float* __restrict__ outvar,
                          float* __restrict__ holo, float* __restrict__ out) {
    int v = blockIdx.x*4 + threadIdx.y;
    int ch = threadIdx.x; // 64
    float dv = dinv[v];
    float acc = Z2y[(size_t)v*DO + ch];
    int e0 = v*DEG;
    #pragma unroll
    for (int k = 0; k < DEG; ++k)
        acc += Z2y[(size_t)(NV + conArr[e0+k])*DO + ch];
    acc *= dv;
    outvar[(size_t)v*DO + ch] = acc;
    float s = acc;
    for (int o = 32; o > 0; o >>= 1) s += __shfl_xor(s, o);
    float mu = s * (1.f/64.f);
    float d = acc - mu;
    float vs = d*d;
    for (int o = 32; o > 0; o >>= 1) vs += __shfl_xor(vs, o);
    float rstd = 1.0f / sqrtf(vs*(1.f/64.f) + 1e-5f);
    float h = d*rstd*gamma[ch] + beta[ch];
    holo[(size_t)v*DO + ch] = h;
    out [(size_t)v*DO + ch] = h;
}

// ---------------- corrections ----------------

__global__ void k_corr_a(const int* __restrict__ breakidx, const float* __restrict__ dinv,
                         const int* __restrict__ conArr, const int* __restrict__ csr_off,
                         const int* __restrict__ csr_v,
                         const float* __restrict__ S1, const float* __restrict__ W1,
                         const float* __restrict__ W2,
                         int* __restrict__ RnG, float* __restrict__ RwG,
                         int* __restrict__ nRG, float* __restrict__ dz2G) {
    __shared__ float W2s[128*64];
    __shared__ int Rn[MAXR];
    __shared__ float Rw[MAXR];
    __shared__ float dh[4][128];
    __shared__ int nR_s;
    int b = blockIdx.x; int tid = threadIdx.x;
    int i = breakidx[b];
    for (int t = tid; t < 128*64; t += 256) W2s[t] = W2[t];
    if (tid == 0) {
        int n = 0; float di = dinv[i];
        if (i >= NV) {
            int c = i - NV;
            int p = csr_off[c], e1 = csr_off[c+1];
            while (p < e1 && n < MAXR-1) {
                int v = csr_v[p]; int m = 1; ++p;
                while (p < e1 && csr_v[p] == v) { ++m; ++p; }
                Rn[n] = v; Rw[n] = (float)m * dinv[v] * di; ++n;
            }
        } else {
            int cn[DEG];
            for (int k = 0; k < DEG; ++k) cn[k] = NV + conArr[i*DEG + k];
            for (int a = 1; a < DEG; ++a) { int key = cn[a]; int bb = a-1;
                while (bb >= 0 && cn[bb] > key) { cn[bb+1] = cn[bb]; --bb; } cn[bb+1] = key; }
            int k = 0;
            while (k < DEG) { int u = cn[k]; int m = 1; ++k;
                while (k < DEG && cn[k] == u) { ++m; ++k; }
                Rn[n] = u; Rw[n] = (float)m * dinv[u] * di; ++n; }
        }
        Rn[n] = i; Rw[n] = di*di; ++n; // self loop, last slot
        nR_s = n;
    }
    __syncthreads();
    int nR = nR_s;
    for (int t = tid; t < nR; t += 256) { RnG[b*MAXR + t] = Rn[t]; RwG[b*MAXR + t] = Rw[t]; }
    if (tid == 0) nRG[b] = nR;
    for (int r0 = 0; r0 < nR; r0 += 4) {
        __syncthreads();
        for (int t = tid; t < 512; t += 256) {
            int ty = t >> 7, k = t & 127;
            int r = r0 + ty;
            if (r < nR) {
                float s1 = S1[(size_t)Rn[r]*DH + k];
                float a = s1 + Rw[r] * W1[64*128 + k];
                dh[ty][k] = fmaxf(a, 0.f) - fmaxf(s1, 0.f);
            }
        }
        __syncthreads();
        int ty2 = tid >> 6, c = tid & 63;
        int r2 = r0 + ty2;
        if (r2 < nR) {
            float acc = 0.f;
            #pragma unroll
            for (int kk = 0; kk < 128; ++kk) acc += dh[ty2][kk] * W2s[kk*64 + c];
            dz2G[((size_t)b*MAXR + r2)*DO + c] = acc;
        }
    }
}

// per graph (serial over its 8 breaks -> deterministic), out[j] += 0.125*(LN(out+delta)-holo[j])
__global__ void k_corr_b(const int* __restrict__ RnG, const float* __restrict__ RwG,
                         const int* __restrict__ nRG, const float* __restrict__ dz2G,
                         const int* __restrict__ breakidx, const float* __restrict__ dinv,
                         const int* __restrict__ conArr, const int* __restrict__ csr_off,
                         const int* __restrict__ csr_v,
                         const float* __restrict__ outvar, const float* __restrict__ holo,
                         const float* __restrict__ gamma, const float* __restrict__ beta,
                         float* __restrict__ out) {
    int g = blockIdx.x;
    int lane = threadIdx.x & 63, wv = threadIdx.x >> 6; // 16 waves
    __shared__ int Jn[MAXJ];
    __shared__ int nJ_s;
    for (int bi = 0; bi < KB; ++bi) {
        int b = g*KB + bi;
        int i = breakidx[b];
        int nR = nRG[b];
        if (i >= NV) {
            int nJ = nR - 1;
            const float* dzi = &dz2G[((size_t)b*MAXR + (nR-1))*DO];
            for (int j0 = wv; j0 < nJ; j0 += 16) {
                int j = RnG[b*MAXR + j0];
                float aji = RwG[b*MAXR + j0];
                float dj = dinv[j];
                float x = outvar[(size_t)j*DO + lane]
                        + aji * dzi[lane]
                        + dj*dj * dz2G[((size_t)b*MAXR + j0)*DO + lane];
                float s = x; for (int o = 32; o > 0; o >>= 1) s += __shfl_xor(s, o);
                float mu = s * (1.f/64.f);
                float d = x - mu;
                float vs = d*d; for (int o = 32; o > 0; o >>= 1) vs += __shfl_xor(vs, o);
                float rstd = 1.0f / sqrtf(vs*(1.f/64.f) + 1e-5f);
                float hn = d*rstd*gamma[lane] + beta[lane];
                out[(size_t)j*DO + lane] += 0.125f * (hn - holo[(size_t)j*DO + lane]);
            }
        } else {
            // variable break node (defensive; analytically never the top-k winner)
            if (threadIdx.x == 0) {
                int n = 0; Jn[n++] = i;
                for (int r = 0; r < nR-1; ++r) {
                    int c = RnG[b*MAXR + r] - NV;
                    for (int p = csr_off[c]; p < csr_off[c+1]; ++p) {
                        int u = csr_v[p];
                        if (p > csr_off[c] && csr_v[p-1] == u) continue;
                        bool found = false;
                        for (int q = 0; q < n; ++q) if (Jn[q] == u) { found = true; break; }
                        if (!found && n < MAXJ) Jn[n++] = u;
                    }
                }
                nJ_s = n;
            }
            __syncthreads();
            int nJ = nJ_s;
            for (int j0 = wv; j0 < nJ; j0 += 16) {
                int j = Jn[j0];
                float dj = dinv[j];
                float x = outvar[(size_t)j*DO + lane];
                for (int k = 0; k < DEG; ++k) {
                    int cn = NV + conArr[j*DEG + k];
                    for (int r = 0; r < nR-1; ++r)
                        if (RnG[b*MAXR + r] == cn) {
                            x += dj * dinv[cn] * dz2G[((size_t)b*MAXR + r)*DO + lane];
                            break;
                        }
                }
                if (j == i) x += dj*dj * dz2G[((size_t)b*MAXR + nR-1)*DO + lane];
                float s = x; for (int o = 32; o > 0; o >>= 1) s += __shfl_xor(s, o);
                float mu = s * (1.f/64.f);
                float d = x - mu;
                float vs = d*d; for (int o = 32; o > 0; o >>= 1) vs += __shfl_xor(vs, o);
                float rstd = 1.0f / sqrtf(vs*(1.f/64.f) + 1e-5f);
                float hn = d*rstd*gamma[lane] + beta[lane];
                out[(size_t)j*DO + lane] += 0.125f * (hn - holo[(size_t)j*DO + lane]);
            }
        }
        __syncthreads();
    }
}

// ---------------- launch ----------------

extern "C" void kernel_launch(void* const* d_in, const int* in_sizes, int n_in,
                              void* d_out, int out_size, void* d_ws, size_t ws_size,
                              hipStream_t stream) {
    const float* vf    = (const float*)d_in[0];
    const float* cf    = (const float*)d_in[1];
    const float* W1    = (const float*)d_in[2];
    const float* b1    = (const float*)d_in[3];
    const float* W2    = (const float*)d_in[4];
    const float* b2    = (const float*)d_in[5];
    const float* gamma = (const float*)d_in[6];
    const float* beta  = (const float*)d_in[7];
    const int*   ei    = (const int*)d_in[8];   // [0..NE) = con, [NE..2NE) = var
    const int*   conArr = ei;
    const int*   varArr = ei + NE;
    float* out = (float*)d_out;

    char* ws = (char*)d_ws;
    size_t off = 0;
    auto alloc = [&](size_t bytes) { char* p = ws + off; off = (off + bytes + 255) & ~(size_t)255; return p; };
    float* dinv    = (float*)alloc(NN*4);
    int*   condeg  = (int*)  alloc(NC*4);
    int*   csr_off = (int*)  alloc((NC+1)*4);
    int*   csr_cur = (int*)  alloc(NC*4);
    int*   csr_e   = (int*)  alloc(NE*4);
    int*   csr_v   = (int*)  alloc(NE*4);
    float* nodeval = (float*)alloc(NN*4);
    int*   breakix = (int*)  alloc(NB*4);
    float* S1      = (float*)alloc((size_t)NN*DH*4);
    float* Zbuf    = (float*)alloc((size_t)NN*DH*4);   // Z1y, later Z2y + outvar
    float* holo    = (float*)alloc((size_t)NV*DO*4);
    int*   RnG     = (int*)  alloc(NB*MAXR*4);
    float* RwG     = (float*)alloc(NB*MAXR*4);
    int*   nRG     = (int*)  alloc(NB*4);
    float* dz2G    = (float*)alloc((size_t)NB*MAXR*DO*4);
    float* Z1y = Zbuf;
    float* Z2y = Zbuf;                      // Z1y dead by then
    float* outvar = Zbuf + (size_t)NN*DO;   // upper part of Zbuf

    k_zero    <<<(NC+255)/256, 256, 0, stream>>>(condeg);
    k_count   <<<(NE+255)/256, 256, 0, stream>>>(conArr, condeg);
    k_scan    <<<1, 256, 0, stream>>>(condeg, csr_off, csr_cur, dinv);
    k_fill    <<<(NE+255)/256, 256, 0, stream>>>(conArr, csr_cur, csr_e);
    k_sortrank<<<(NC+3)/4, 256, 0, stream>>>(csr_off, csr_e, varArr, csr_v);
    k_nodeval <<<(NN+255)/256, 256, 0, stream>>>(dinv, conArr, csr_off, csr_v, nodeval);
    k_topk    <<<G_, 256, 0, stream>>>(nodeval, breakix);

    k_gemm1   <<<NN/32, 256, 0, stream>>>(vf, cf, W1, b1, dinv, Z1y);
    k_spmm1   <<<NN/2, 256, 0, stream>>>(Z1y, dinv, conArr, csr_off, csr_v, S1);
    k_gemm2   <<<NN/32, 256, 0, stream>>>(S1, W2, b2, dinv, Z2y);
    k_spmm2ln <<<NV/4, dim3(64,4), 0, stream>>>(Z2y, dinv, conArr, gamma, beta, outvar, holo, out);

    k_corr_a  <<<NB, 256, 0, stream>>>(breakix, dinv, conArr, csr_off, csr_v,
                                       S1, W1, W2, RnG, RwG, nRG, dz2G);
    k_corr_b  <<<G_, 1024, 0, stream>>>(RnG, RwG, nRG, dz2G, breakix, dinv, conArr,
                                        csr_off, csr_v, outvar, holo, gamma, beta, out);
}